// Round 14
// baseline (122.181 us; speedup 1.0000x reference)
//
#include <hip/hip_runtime.h>
#include <hip/hip_bf16.h>
#include <math.h>

#define DIMX 1024
#define HEADSX 16
#define HDX 64
#define BBX 2
#define SSX 2048
#define MMX (BBX*SSX)   // 4096 rows

typedef __bf16 bf16x8 __attribute__((ext_vector_type(8)));
typedef __bf16 bf16x4 __attribute__((ext_vector_type(4)));
typedef float  f32x4  __attribute__((ext_vector_type(4)));

#define NEGF (-1e30f)
#define QSCALE 0.18033688011112042f   // (1/sqrt(64)) * log2(e), folded into Q

// async 16B global->LDS. LDS dest must be wave-uniform base; HW adds lane*16.
static __device__ __forceinline__ void gload16(const void* g, void* l) {
  __builtin_amdgcn_global_load_lds(
      (const __attribute__((address_space(1))) unsigned int*)g,
      (__attribute__((address_space(3))) unsigned int*)l, 16, 0, 0);
}

// ------- kernel 1: fused prep: x fp32->bf16  +  W transpose->bf16 -------
// blocks [0,2048): x convert 8/thread; [2048,3072): W transpose 64x64 tiles.
__global__ __launch_bounds__(256) void k_prep(
    const float* __restrict__ x, const float* __restrict__ Wq,
    const float* __restrict__ Wk, const float* __restrict__ Wv,
    const float* __restrict__ Wo, __bf16* __restrict__ xb,
    __bf16* __restrict__ wqkvT, __bf16* __restrict__ woT) {
  const int bid = blockIdx.x;
  if (bid < 2048) {
    int i = (bid * 256 + threadIdx.x) * 8;
    float4 v0 = *(const float4*)&x[i];
    float4 v1 = *(const float4*)&x[i + 4];
    bf16x8 o = { (__bf16)v0.x, (__bf16)v0.y, (__bf16)v0.z, (__bf16)v0.w,
                 (__bf16)v1.x, (__bf16)v1.y, (__bf16)v1.z, (__bf16)v1.w };
    *(bf16x8*)&xb[i] = o;
    return;
  }
  __shared__ __bf16 tile[64][65];
  const int wb = bid - 2048;
  const int mat = wb >> 8, t8 = wb & 255;
  const float* src = (mat == 0) ? Wq : (mat == 1) ? Wk : (mat == 2) ? Wv : Wo;
  __bf16* dst = (mat < 3) ? (wqkvT + (size_t)mat * DIMX * DIMX) : woT;
  const int tx = t8 & 15, ty = t8 >> 4;
  const int k0 = ty * 64, n0 = tx * 64;
  #pragma unroll
  for (int rep = 0; rep < 16; ++rep) {
    int idx = rep * 256 + threadIdx.x;
    int r = idx >> 6, c = idx & 63;
    tile[r][c] = (__bf16)src[(size_t)(k0 + r) * DIMX + n0 + c];
  }
  __syncthreads();
  #pragma unroll
  for (int rep = 0; rep < 16; ++rep) {
    int idx = rep * 256 + threadIdx.x;
    int r = idx >> 6, c = idx & 63;           // r = local n, c = local k
    dst[(size_t)(n0 + r) * DIMX + k0 + c] = tile[c][r];
  }
}

// ---------------- kernel 3: QKV GEMM, 128x128 tile, BK=32 (r7 form) ----------------
// proj is BLOCK-UNIFORM (n-panels are 128-aligned): V-blocks route their
// epilogue through LDS (Vst) so the [d][s] transposed layout stores as
// coalesced 16B chunks instead of 64 scalar stores at 4KB lane stride.
// LDS 16+32 = 48 KB -> still exactly 3 blocks/CU (768 blocks): no occ loss.
__global__ __launch_bounds__(256) void k_gemm_qkv(
    const __bf16* __restrict__ A,    // [4096][1024]
    const __bf16* __restrict__ Bt,   // [3072][1024]
    const float* __restrict__ b0, const float* __restrict__ b1,
    const float* __restrict__ b2,
    __bf16* __restrict__ qb, __bf16* __restrict__ kb, __bf16* __restrict__ vtb) {
  constexpr int BK = 32, K = 1024;
  __shared__ __bf16 As[128 * BK];
  __shared__ __bf16 Bs[128 * BK];
  __shared__ __bf16 Vst[2][64 * 128];   // 32 KB, V-epilogue staging only
  const int tid = threadIdx.x, lane = tid & 63, wave = tid >> 6;
  const int g = lane >> 4, r16 = lane & 15;
  const int wm = wave & 1, wn = wave >> 1;
  const int id = blockIdx.x;                 // 768 blocks = 8 XCD x 96
  const int xcd = id & 7, j96 = id >> 3;
  const int m0 = (xcd * 4 + (j96 & 3)) * 128;   // 32 m-tiles
  const int n0 = (j96 >> 2) * 128;              // 24 n-tiles

  f32x4 acc[4][4] = {};

  for (int k0 = 0; k0 < K; k0 += BK) {
    __syncthreads();
    #pragma unroll
    for (int i = 0; i < 2; ++i) {
      int c = wave * 64 + lane + 256 * i;       // chunk id (512 x 16B per tile)
      gload16(&A [(size_t)(m0 + (c >> 2)) * K + k0 + (c & 3) * 8],
              (char*)As + (size_t)(wave * 64 + 256 * i) * 16);
      gload16(&Bt[(size_t)(n0 + (c >> 2)) * K + k0 + (c & 3) * 8],
              (char*)Bs + (size_t)(wave * 64 + 256 * i) * 16);
    }
    __syncthreads();
    bf16x8 af[4], bfr[4];
    #pragma unroll
    for (int i = 0; i < 4; ++i)
      af[i]  = *(const bf16x8*)&As[(wm * 64 + i * 16 + r16) * BK + g * 8];
    #pragma unroll
    for (int j = 0; j < 4; ++j)
      bfr[j] = *(const bf16x8*)&Bs[(wn * 64 + j * 16 + r16) * BK + g * 8];
    #pragma unroll
    for (int i = 0; i < 4; ++i)
      #pragma unroll
      for (int j = 0; j < 4; ++j)
        acc[i][j] = __builtin_amdgcn_mfma_f32_16x16x32_bf16(af[i], bfr[j],
                                                            acc[i][j], 0, 0, 0);
  }

  const int proj = n0 >> 10;                 // block-uniform: 0=Q,1=K,2=V
  if (proj == 2) {
    // ---- V: stage (d,s)-transposed tile in LDS, store coalesced ----
    const int w0 = n0 - 2048;
    #pragma unroll
    for (int i = 0; i < 4; ++i)
      #pragma unroll
      for (int j = 0; j < 4; ++j)
        #pragma unroll
        for (int r = 0; r < 4; ++r) {
          int sl = wm * 64 + i * 16 + 4 * g + r;     // s_local 0..127
          int d  = j * 16 + r16;                      // 0..63
          float v = acc[i][j][r] + b2[w0 + wn * 64 + d];
          int cs = (sl >> 3) ^ (d & 7);               // swizzled s-chunk
          Vst[wn][d * 128 + cs * 8 + (sl & 7)] = (__bf16)v;
        }
    __syncthreads();
    const int h0 = w0 >> 6;                  // head for wn=0 half
    const int b = m0 >> 11, s0g = m0 & 2047;
    #pragma unroll
    for (int i = 0; i < 8; ++i) {
      int c = tid + 256 * i;                 // 2048 chunks of 16B
      int hh = c >> 10;                      // half (= wn at write time)
      int d  = (c >> 4) & 63;
      int j  = c & 15;                       // s-chunk
      int cs = j ^ (d & 7);
      bf16x8 vv = *(const bf16x8*)&Vst[hh][d * 128 + cs * 8];
      size_t row = (size_t)((b * HEADSX + h0 + hh) * HDX + d);
      *(bf16x8*)&vtb[row * SSX + s0g + j * 8] = vv;
    }
  } else {
    #pragma unroll
    for (int i = 0; i < 4; ++i)
      #pragma unroll
      for (int j = 0; j < 4; ++j)
        #pragma unroll
        for (int r = 0; r < 4; ++r) {
          int m = m0 + wm * 64 + i * 16 + 4 * g + r;
          int n = n0 + wn * 64 + j * 16 + r16;
          int w = n & 1023, h = w >> 6, d = w & 63;
          float v = acc[i][j][r] + ((proj == 0) ? b0[w] : b1[w]);
          int b = m >> 11, s = m & 2047, bh = b * HEADSX + h;
          if (proj == 0)
            qb[((size_t)bh * SSX + s) * HDX + d] = (__bf16)(v * QSCALE);
          else
            kb[((size_t)bh * SSX + s) * HDX + d] = (__bf16)v;
        }
  }
}

// ---------------- kernel 5: output GEMM, 128x64 tile, BK=32 (r7 form) ----------------
__global__ __launch_bounds__(256) void k_gemm_out(
    const __bf16* __restrict__ A,    // ctx [4096][1024]
    const __bf16* __restrict__ Bt,   // WoT [1024][1024]
    const float* __restrict__ bias, float* __restrict__ outf) {
  constexpr int BK = 32, K = 1024;
  __shared__ __bf16 As[128 * BK];    // 8 KB
  __shared__ __bf16 Bs[64 * BK];     // 4 KB
  const int tid = threadIdx.x, lane = tid & 63, wave = tid >> 6;
  const int g = lane >> 4, r16 = lane & 15;
  const int wm = wave & 1, wn = wave >> 1;
  const int id = blockIdx.x;                 // 512 blocks = 8 XCD x 64
  const int xcd = id & 7, j64 = id >> 3;
  const int m0 = (xcd * 4 + (j64 & 3)) * 128;   // 32 m-tiles
  const int n0 = (j64 >> 2) * 64;               // 16 n-tiles

  f32x4 acc[4][2] = {};

  for (int k0 = 0; k0 < K; k0 += BK) {
    __syncthreads();
    #pragma unroll
    for (int i = 0; i < 2; ++i) {
      int c = wave * 64 + lane + 256 * i;      // A: 512 chunks
      gload16(&A [(size_t)(m0 + (c >> 2)) * K + k0 + (c & 3) * 8],
              (char*)As + (size_t)(wave * 64 + 256 * i) * 16);
    }
    {
      int c = tid;                             // B: 256 chunks
      gload16(&Bt[(size_t)(n0 + (c >> 2)) * K + k0 + (c & 3) * 8],
              (char*)Bs + (size_t)(wave * 64) * 16);
    }
    __syncthreads();
    bf16x8 af[4], bfr[2];
    #pragma unroll
    for (int i = 0; i < 4; ++i)
      af[i]  = *(const bf16x8*)&As[(wm * 64 + i * 16 + r16) * BK + g * 8];
    #pragma unroll
    for (int j = 0; j < 2; ++j)
      bfr[j] = *(const bf16x8*)&Bs[(wn * 32 + j * 16 + r16) * BK + g * 8];
    #pragma unroll
    for (int i = 0; i < 4; ++i)
      #pragma unroll
      for (int j = 0; j < 2; ++j)
        acc[i][j] = __builtin_amdgcn_mfma_f32_16x16x32_bf16(af[i], bfr[j],
                                                            acc[i][j], 0, 0, 0);
  }

  #pragma unroll
  for (int i = 0; i < 4; ++i)
    #pragma unroll
    for (int j = 0; j < 2; ++j)
      #pragma unroll
      for (int r = 0; r < 4; ++r) {
        int m = m0 + wm * 64 + i * 16 + 4 * g + r;
        int n = n0 + wn * 32 + j * 16 + r16;
        outf[(size_t)m * DIMX + n] = acc[i][j][r] + bias[n];
      }
}

// -------- kernel 4: causal flash attention (r6 body + coalesced epilogue) --------
// Complementary pairing: block p handles qL=p (ntL tiles) and qH=31-p (ntH)
// -> uniform 33 kv-tiles/block. Core loop unchanged from the measured optimum.
// Epilogue now stages ctx^T->ctx through Ks (dead after the last barrier) so
// stores are 16B coalesced instead of 16 scalar stores at 2KB lane stride.
__global__ __launch_bounds__(256, 2) void k_attn(
    const __bf16* __restrict__ qb, const __bf16* __restrict__ kb,
    const __bf16* __restrict__ vtb, __bf16* __restrict__ ctxb) {
  const int tid = threadIdx.x;
  const int lane = tid & 63, wq = tid >> 6;
  const int g = lane >> 4, r16 = lane & 15;

  // XCD-chunked mapping: id%8 = XCD; 4 consecutive bh per XCD.
  const int id = blockIdx.x;
  const int xcd = id & 7, idx = id >> 3;
  const int bh = xcd * 4 + (idx & 3);
  const int p  = idx >> 2;                 // pair index 0..15
  const int b = bh >> 4, h = bh & 15;

  const int ntL = p + 1, ntH = 32 - p;     // ntL <= 16 < ntH always
  const int q0L = p * 64 + wq * 16;
  const int q0H = (31 - p) * 64 + wq * 16;

  const __bf16* Q  = qb  + (size_t)bh * SSX * HDX;
  const __bf16* Kp = kb  + (size_t)bh * SSX * HDX;
  const __bf16* Vt = vtb + (size_t)bh * HDX * SSX;

  __shared__ __bf16 Ks[2][64 * 64];    // 2 x 8 KB (reused as epilogue staging)
  __shared__ __bf16 Vs[2][64 * 64];    // 2 x 8 KB
  __shared__ unsigned Pld[4][512];     // per-wave P^T scratch, 8 KB

  bf16x8 qfL[2], qfH[2];
  qfL[0] = *(const bf16x8*)&Q[(size_t)(q0L + r16) * HDX + g * 8];
  qfL[1] = *(const bf16x8*)&Q[(size_t)(q0L + r16) * HDX + 32 + g * 8];
  qfH[0] = *(const bf16x8*)&Q[(size_t)(q0H + r16) * HDX + g * 8];
  qfH[1] = *(const bf16x8*)&Q[(size_t)(q0H + r16) * HDX + 32 + g * 8];

  f32x4 accL[4] = {}, accH[4] = {};    // ctx^T: acc[j2][r]=ctx[d=j2*16+4g+r][q=r16]
  float mrunL = NEGF, lrunL = 0.f;
  float mrunH = NEGF, lrunH = 0.f;

  // stage tile t (64 kv x 64) of K and V. LDS chunk (r,cb) <- global (r, cb^(r&7))
  auto STAGE = [&](int buf, int t) {
    const int kv0 = t * 64;
    #pragma unroll
    for (int i = 0; i < 2; ++i) {
      int c = tid + 256 * i;
      int r = c >> 3;
      int cb = (c & 7) ^ (r & 7);
      gload16(&Kp[(size_t)(kv0 + r) * HDX + cb * 8],
              (char*)Ks[buf] + (size_t)(wq * 64 + 256 * i) * 16);
      gload16(&Vt[(size_t)r * SSX + kv0 + cb * 8],
              (char*)Vs[buf] + (size_t)(wq * 64 + 256 * i) * 16);
    }
  };

  // one 16q x 64k sub-tile step against the staged kv-tile
  auto SUBTILE = [&](const bf16x8* qf, f32x4* acc, float& mrun, float& lrun,
                     int qrow, bool last, int kv0, int cur) {
    // ---- S^T = K Q^T: sac[jj][r] = S[k=kv0+16jj+4g+r][q=r16] (pre-scaled) ----
    f32x4 sac[4] = {};
    __builtin_amdgcn_s_setprio(1);
    #pragma unroll
    for (int kk = 0; kk < 2; ++kk)
      #pragma unroll
      for (int jj = 0; jj < 4; ++jj) {
        int rr = jj * 16 + r16;
        bf16x8 kf = *(const bf16x8*)
            &Ks[cur][rr * 64 + (((kk << 2) + g) ^ (rr & 7)) * 8];
        sac[jj] = __builtin_amdgcn_mfma_f32_16x16x32_bf16(kf, qf[kk], sac[jj],
                                                          0, 0, 0);
      }
    __builtin_amdgcn_s_setprio(0);

    // ---- causal mask (diagonal tile only), per-lane max ----
    float pv[4][4];
    float mt = NEGF;
    #pragma unroll
    for (int jj = 0; jj < 4; ++jj)
      #pragma unroll
      for (int r = 0; r < 4; ++r) {
        float s = sac[jj][r];
        if (last) {
          int kcol = kv0 + jj * 16 + 4 * g + r;
          s = (kcol > qrow) ? NEGF : s;
        }
        pv[jj][r] = s;
        mt = fmaxf(mt, s);
      }
    mt = fmaxf(mt, __shfl_xor(mt, 16));
    mt = fmaxf(mt, __shfl_xor(mt, 32));

    if (__any(mt > mrun)) {          // T13 defer-max (exact: P<=1 when skipped)
      float mnew = fmaxf(mrun, mt);
      float fac = exp2f(mrun - mnew);
      mrun = mnew;
      lrun *= fac;
      #pragma unroll
      for (int j2 = 0; j2 < 4; ++j2)
        #pragma unroll
        for (int r = 0; r < 4; ++r)
          acc[j2][r] *= fac;
    }
    float rs = 0.f;
    #pragma unroll
    for (int jj = 0; jj < 4; ++jj)
      #pragma unroll
      for (int r = 0; r < 4; ++r) {
        float px = exp2f(pv[jj][r] - mrun);
        pv[jj][r] = px;
        rs += px;
      }
    lrun += rs;                      // lane-partial; cross-g reduced at end

    // ---- pack P^T to bf16, store transposed (quad-swizzled dwords) ----
    #pragma unroll
    for (int jj = 0; jj < 4; ++jj)
      #pragma unroll
      for (int rp = 0; rp < 2; ++rp) {
        unsigned w;
        asm("v_cvt_pk_bf16_f32 %0, %1, %2"
            : "=v"(w) : "v"(pv[jj][2 * rp]), "v"(pv[jj][2 * rp + 1]));
        int c = jj * 8 + g * 2 + rp;                       // k/2
        int addr = r16 * 32 + (((c >> 2) ^ (r16 & 7)) << 2) + (c & 3);
        Pld[wq][addr] = w;
      }

    // ---- ctx^T += V^T P ----
    bf16x8 pf[2];
    #pragma unroll
    for (int half = 0; half < 2; ++half) {
      int c = half * 16 + g * 4;
      int addr = r16 * 32 + (((c >> 2) ^ (r16 & 7)) << 2);
      pf[half] = *(const bf16x8*)&Pld[wq][addr];
    }
    __builtin_amdgcn_s_setprio(1);
    #pragma unroll
    for (int j2 = 0; j2 < 4; ++j2)
      #pragma unroll
      for (int half = 0; half < 2; ++half) {
        int dd = j2 * 16 + r16;
        bf16x8 vf = *(const bf16x8*)
            &Vs[cur][dd * 64 + (((half << 2) + g) ^ (dd & 7)) * 8];
        acc[j2] = __builtin_amdgcn_mfma_f32_16x16x32_bf16(vf, pf[half],
                                                          acc[j2], 0, 0, 0);
      }
    __builtin_amdgcn_s_setprio(0);
  };

  STAGE(0, 0);
  __syncthreads();

  for (int t = 0; t < ntH; ++t) {
    const int cur = t & 1;
    if (t + 1 < ntH) STAGE(cur ^ 1, t + 1);   // async prefetch next tile
    const int kv0 = t * 64;

    SUBTILE(qfH, accH, mrunH, lrunH, q0H + r16, t == ntH - 1, kv0, cur);
    if (t < ntL)
      SUBTILE(qfL, accL, mrunL, lrunL, q0L + r16, t == ntL - 1, kv0, cur);

    __syncthreads();   // drains prefetch (vmcnt) + all LDS reads (lgkm)
  }
  // (last barrier above: Ks/Vs now dead -> reuse Ks as epilogue staging)

  // ---- stage normalized ctx tiles [64q][64d] into Ks (chunk-swizzled) ----
  auto STAGE_OUT = [&](f32x4* acc, float lrun, int slot) {
    lrun += __shfl_xor(lrun, 16);
    lrun += __shfl_xor(lrun, 32);
    const float inv = 1.f / lrun;
    const int q = wq * 16 + r16;
    #pragma unroll
    for (int j2 = 0; j2 < 4; ++j2)
      #pragma unroll
      for (int r = 0; r < 4; ++r) {
        int d = j2 * 16 + 4 * g + r;
        int cs = (d >> 3) ^ (q & 7);
        Ks[slot][q * 64 + cs * 8 + (d & 7)] = (__bf16)(acc[j2][r] * inv);
      }
  };
  STAGE_OUT(accH, lrunH, 0);
  STAGE_OUT(accL, lrunL, 1);
  __syncthreads();

  // ---- coalesced 16B stores: 1024 chunks (2 tiles x 64q x 8), 4/thread ----
  #pragma unroll
  for (int i = 0; i < 4; ++i) {
    int c = tid + 256 * i;
    int slot = c >> 9;                       // 0: qH tile, 1: qL tile
    int ql = (c >> 3) & 63, j = c & 7;
    int cs = j ^ (ql & 7);
    bf16x8 vv = *(const bf16x8*)&Ks[slot][ql * 64 + cs * 8];
    int qg = (slot ? p : (31 - p)) * 64 + ql;
    *(bf16x8*)&ctxb[((size_t)(b * SSX + qg)) * DIMX + h * HDX + j * 8] = vv;
  }
}

extern "C" void kernel_launch(void* const* d_in, const int* in_sizes, int n_in,
                              void* d_out, int out_size, void* d_ws,
                              size_t ws_size, hipStream_t stream) {
  const float* x  = (const float*)d_in[0];
  const float* Wq = (const float*)d_in[1];
  const float* bq = (const float*)d_in[2];
  const float* Wk = (const float*)d_in[3];
  const float* bk = (const float*)d_in[4];
  const float* Wv = (const float*)d_in[5];
  const float* bv = (const float*)d_in[6];
  const float* Wo = (const float*)d_in[7];
  const float* bo = (const float*)d_in[8];
  float* out = (float*)d_out;

  char* ws = (char*)d_ws;                       // needs 40 MB
  __bf16* xb    = (__bf16*)(ws);                // 8 MB, reused as ctxb later
  __bf16* wqkvT = (__bf16*)(ws + ((size_t)8  << 20));  // 6 MB
  __bf16* woT   = (__bf16*)(ws + ((size_t)14 << 20));  // 2 MB
  __bf16* qb    = (__bf16*)(ws + ((size_t)16 << 20));  // 8 MB
  __bf16* kb    = (__bf16*)(ws + ((size_t)24 << 20));  // 8 MB
  __bf16* vtb   = (__bf16*)(ws + ((size_t)32 << 20));  // 8 MB (V^T)
  __bf16* ctxb  = xb;   // x dead after QKV GEMM

  k_prep<<<3072, 256, 0, stream>>>(x, Wq, Wk, Wv, Wo, xb, wqkvT, woT);
  k_gemm_qkv<<<768, 256, 0, stream>>>(xb, wqkvT, bq, bk, bv, qb, kb, vtb);
  k_attn<<<512, 256, 0, stream>>>(qb, kb, vtb, ctxb);
  k_gemm_out<<<512, 256, 0, stream>>>(ctxb, woT, bo, out);
}

// Round 15
// 115.991 us; speedup vs baseline: 1.0534x; 1.0534x over previous
//
#include <hip/hip_runtime.h>
#include <hip/hip_bf16.h>
#include <math.h>

#define DIMX 1024
#define HEADSX 16
#define HDX 64
#define BBX 2
#define SSX 2048
#define MMX (BBX*SSX)   // 4096 rows

typedef __bf16 bf16x8 __attribute__((ext_vector_type(8)));
typedef __bf16 bf16x4 __attribute__((ext_vector_type(4)));
typedef float  f32x4  __attribute__((ext_vector_type(4)));

#define NEGF (-1e30f)
#define QSCALE 0.18033688011112042f   // (1/sqrt(64)) * log2(e), folded into Q

// async 16B global->LDS. LDS dest must be wave-uniform base; HW adds lane*16.
static __device__ __forceinline__ void gload16(const void* g, void* l) {
  __builtin_amdgcn_global_load_lds(
      (const __attribute__((address_space(1))) unsigned int*)g,
      (__attribute__((address_space(3))) unsigned int*)l, 16, 0, 0);
}

// ------- kernel 1: fused prep: x fp32->bf16  +  W transpose->bf16 -------
// blocks [0,2048): x convert 8/thread; [2048,3072): W transpose 64x64 tiles.
__global__ __launch_bounds__(256) void k_prep(
    const float* __restrict__ x, const float* __restrict__ Wq,
    const float* __restrict__ Wk, const float* __restrict__ Wv,
    const float* __restrict__ Wo, __bf16* __restrict__ xb,
    __bf16* __restrict__ wqkvT, __bf16* __restrict__ woT) {
  const int bid = blockIdx.x;
  if (bid < 2048) {
    int i = (bid * 256 + threadIdx.x) * 8;
    float4 v0 = *(const float4*)&x[i];
    float4 v1 = *(const float4*)&x[i + 4];
    bf16x8 o = { (__bf16)v0.x, (__bf16)v0.y, (__bf16)v0.z, (__bf16)v0.w,
                 (__bf16)v1.x, (__bf16)v1.y, (__bf16)v1.z, (__bf16)v1.w };
    *(bf16x8*)&xb[i] = o;
    return;
  }
  __shared__ __bf16 tile[64][65];
  const int wb = bid - 2048;
  const int mat = wb >> 8, t8 = wb & 255;
  const float* src = (mat == 0) ? Wq : (mat == 1) ? Wk : (mat == 2) ? Wv : Wo;
  __bf16* dst = (mat < 3) ? (wqkvT + (size_t)mat * DIMX * DIMX) : woT;
  const int tx = t8 & 15, ty = t8 >> 4;
  const int k0 = ty * 64, n0 = tx * 64;
  #pragma unroll
  for (int rep = 0; rep < 16; ++rep) {
    int idx = rep * 256 + threadIdx.x;
    int r = idx >> 6, c = idx & 63;
    tile[r][c] = (__bf16)src[(size_t)(k0 + r) * DIMX + n0 + c];
  }
  __syncthreads();
  #pragma unroll
  for (int rep = 0; rep < 16; ++rep) {
    int idx = rep * 256 + threadIdx.x;
    int r = idx >> 6, c = idx & 63;           // r = local n, c = local k
    dst[(size_t)(n0 + r) * DIMX + k0 + c] = tile[c][r];
  }
}

// ---------------- kernel 3: QKV GEMM, 128x128 tile, BK=32 (r7 form) ----------------
// 2-barrier m97-style loop; scatter epilogue. Measured optimum: explicit dbuf
// (r10), BK=64+swizzle (r8), and LDS-staged V epilogue (r14) all regressed.
__global__ __launch_bounds__(256) void k_gemm_qkv(
    const __bf16* __restrict__ A,    // [4096][1024]
    const __bf16* __restrict__ Bt,   // [3072][1024]
    const float* __restrict__ b0, const float* __restrict__ b1,
    const float* __restrict__ b2,
    __bf16* __restrict__ qb, __bf16* __restrict__ kb, __bf16* __restrict__ vtb) {
  constexpr int BK = 32, K = 1024;
  __shared__ __bf16 As[128 * BK];
  __shared__ __bf16 Bs[128 * BK];
  const int tid = threadIdx.x, lane = tid & 63, wave = tid >> 6;
  const int g = lane >> 4, r16 = lane & 15;
  const int wm = wave & 1, wn = wave >> 1;
  const int id = blockIdx.x;                 // 768 blocks = 8 XCD x 96
  const int xcd = id & 7, j96 = id >> 3;
  const int m0 = (xcd * 4 + (j96 & 3)) * 128;   // 32 m-tiles
  const int n0 = (j96 >> 2) * 128;              // 24 n-tiles

  f32x4 acc[4][4] = {};

  for (int k0 = 0; k0 < K; k0 += BK) {
    __syncthreads();
    #pragma unroll
    for (int i = 0; i < 2; ++i) {
      int c = wave * 64 + lane + 256 * i;       // chunk id (512 x 16B per tile)
      gload16(&A [(size_t)(m0 + (c >> 2)) * K + k0 + (c & 3) * 8],
              (char*)As + (size_t)(wave * 64 + 256 * i) * 16);
      gload16(&Bt[(size_t)(n0 + (c >> 2)) * K + k0 + (c & 3) * 8],
              (char*)Bs + (size_t)(wave * 64 + 256 * i) * 16);
    }
    __syncthreads();
    bf16x8 af[4], bfr[4];
    #pragma unroll
    for (int i = 0; i < 4; ++i)
      af[i]  = *(const bf16x8*)&As[(wm * 64 + i * 16 + r16) * BK + g * 8];
    #pragma unroll
    for (int j = 0; j < 4; ++j)
      bfr[j] = *(const bf16x8*)&Bs[(wn * 64 + j * 16 + r16) * BK + g * 8];
    #pragma unroll
    for (int i = 0; i < 4; ++i)
      #pragma unroll
      for (int j = 0; j < 4; ++j)
        acc[i][j] = __builtin_amdgcn_mfma_f32_16x16x32_bf16(af[i], bfr[j],
                                                            acc[i][j], 0, 0, 0);
  }

  #pragma unroll
  for (int i = 0; i < 4; ++i) {
    #pragma unroll
    for (int j = 0; j < 4; ++j) {
      #pragma unroll
      for (int r = 0; r < 4; ++r) {
        int m = m0 + wm * 64 + i * 16 + 4 * g + r;   // C row = (lane>>4)*4+reg
        int n = n0 + wn * 64 + j * 16 + r16;         // C col = lane&15
        float v = acc[i][j][r];
        int proj = n >> 10, w = n & 1023, h = w >> 6, d = w & 63;
        const float* bp = (proj == 0) ? b0 : (proj == 1) ? b1 : b2;
        v += bp[w];
        int b = m >> 11, s = m & 2047, bh = b * HEADSX + h;
        if (proj == 0)      qb [((size_t)bh * SSX + s) * HDX + d] =
                                (__bf16)(v * QSCALE);
        else if (proj == 1) kb [((size_t)bh * SSX + s) * HDX + d] = (__bf16)v;
        else                vtb[((size_t)bh * HDX + d) * SSX + s] = (__bf16)v;
      }
    }
  }
}

// ---------------- kernel 5: output GEMM, 128x64 tile, BK=32 (r7 form) ----------------
__global__ __launch_bounds__(256) void k_gemm_out(
    const __bf16* __restrict__ A,    // ctx [4096][1024]
    const __bf16* __restrict__ Bt,   // WoT [1024][1024]
    const float* __restrict__ bias, float* __restrict__ outf) {
  constexpr int BK = 32, K = 1024;
  __shared__ __bf16 As[128 * BK];    // 8 KB
  __shared__ __bf16 Bs[64 * BK];     // 4 KB
  const int tid = threadIdx.x, lane = tid & 63, wave = tid >> 6;
  const int g = lane >> 4, r16 = lane & 15;
  const int wm = wave & 1, wn = wave >> 1;
  const int id = blockIdx.x;                 // 512 blocks = 8 XCD x 64
  const int xcd = id & 7, j64 = id >> 3;
  const int m0 = (xcd * 4 + (j64 & 3)) * 128;   // 32 m-tiles
  const int n0 = (j64 >> 2) * 64;               // 16 n-tiles

  f32x4 acc[4][2] = {};

  for (int k0 = 0; k0 < K; k0 += BK) {
    __syncthreads();
    #pragma unroll
    for (int i = 0; i < 2; ++i) {
      int c = wave * 64 + lane + 256 * i;      // A: 512 chunks
      gload16(&A [(size_t)(m0 + (c >> 2)) * K + k0 + (c & 3) * 8],
              (char*)As + (size_t)(wave * 64 + 256 * i) * 16);
    }
    {
      int c = tid;                             // B: 256 chunks
      gload16(&Bt[(size_t)(n0 + (c >> 2)) * K + k0 + (c & 3) * 8],
              (char*)Bs + (size_t)(wave * 64) * 16);
    }
    __syncthreads();
    bf16x8 af[4], bfr[2];
    #pragma unroll
    for (int i = 0; i < 4; ++i)
      af[i]  = *(const bf16x8*)&As[(wm * 64 + i * 16 + r16) * BK + g * 8];
    #pragma unroll
    for (int j = 0; j < 2; ++j)
      bfr[j] = *(const bf16x8*)&Bs[(wn * 32 + j * 16 + r16) * BK + g * 8];
    #pragma unroll
    for (int i = 0; i < 4; ++i)
      #pragma unroll
      for (int j = 0; j < 2; ++j)
        acc[i][j] = __builtin_amdgcn_mfma_f32_16x16x32_bf16(af[i], bfr[j],
                                                            acc[i][j], 0, 0, 0);
  }

  #pragma unroll
  for (int i = 0; i < 4; ++i)
    #pragma unroll
    for (int j = 0; j < 2; ++j)
      #pragma unroll
      for (int r = 0; r < 4; ++r) {
        int m = m0 + wm * 64 + i * 16 + 4 * g + r;
        int n = n0 + wn * 32 + j * 16 + r16;
        outf[(size_t)m * DIMX + n] = acc[i][j][r] + bias[n];
      }
}

// -------- kernel 4: causal flash attention (r6 body + coalesced epilogue) --------
// Complementary pairing: block p handles qL=p (ntL tiles) and qH=31-p (ntH)
// -> uniform 33 kv-tiles/block. Core loop = measured optimum (r7-r12 levers
// all neutral-to-negative). Epilogue stages ctx^T->ctx through dead Ks for
// coalesced 16B stores (r14: neutral-to-marginally-positive, kept).
__global__ __launch_bounds__(256, 2) void k_attn(
    const __bf16* __restrict__ qb, const __bf16* __restrict__ kb,
    const __bf16* __restrict__ vtb, __bf16* __restrict__ ctxb) {
  const int tid = threadIdx.x;
  const int lane = tid & 63, wq = tid >> 6;
  const int g = lane >> 4, r16 = lane & 15;

  // XCD-chunked mapping: id%8 = XCD; 4 consecutive bh per XCD.
  const int id = blockIdx.x;
  const int xcd = id & 7, idx = id >> 3;
  const int bh = xcd * 4 + (idx & 3);
  const int p  = idx >> 2;                 // pair index 0..15
  const int b = bh >> 4, h = bh & 15;

  const int ntL = p + 1, ntH = 32 - p;     // ntL <= 16 < ntH always
  const int q0L = p * 64 + wq * 16;
  const int q0H = (31 - p) * 64 + wq * 16;

  const __bf16* Q  = qb  + (size_t)bh * SSX * HDX;
  const __bf16* Kp = kb  + (size_t)bh * SSX * HDX;
  const __bf16* Vt = vtb + (size_t)bh * HDX * SSX;

  __shared__ __bf16 Ks[2][64 * 64];    // 2 x 8 KB (reused as epilogue staging)
  __shared__ __bf16 Vs[2][64 * 64];    // 2 x 8 KB
  __shared__ unsigned Pld[4][512];     // per-wave P^T scratch, 8 KB

  bf16x8 qfL[2], qfH[2];
  qfL[0] = *(const bf16x8*)&Q[(size_t)(q0L + r16) * HDX + g * 8];
  qfL[1] = *(const bf16x8*)&Q[(size_t)(q0L + r16) * HDX + 32 + g * 8];
  qfH[0] = *(const bf16x8*)&Q[(size_t)(q0H + r16) * HDX + g * 8];
  qfH[1] = *(const bf16x8*)&Q[(size_t)(q0H + r16) * HDX + 32 + g * 8];

  f32x4 accL[4] = {}, accH[4] = {};    // ctx^T: acc[j2][r]=ctx[d=j2*16+4g+r][q=r16]
  float mrunL = NEGF, lrunL = 0.f;
  float mrunH = NEGF, lrunH = 0.f;

  // stage tile t (64 kv x 64) of K and V. LDS chunk (r,cb) <- global (r, cb^(r&7))
  auto STAGE = [&](int buf, int t) {
    const int kv0 = t * 64;
    #pragma unroll
    for (int i = 0; i < 2; ++i) {
      int c = tid + 256 * i;
      int r = c >> 3;
      int cb = (c & 7) ^ (r & 7);
      gload16(&Kp[(size_t)(kv0 + r) * HDX + cb * 8],
              (char*)Ks[buf] + (size_t)(wq * 64 + 256 * i) * 16);
      gload16(&Vt[(size_t)r * SSX + kv0 + cb * 8],
              (char*)Vs[buf] + (size_t)(wq * 64 + 256 * i) * 16);
    }
  };

  // one 16q x 64k sub-tile step against the staged kv-tile
  auto SUBTILE = [&](const bf16x8* qf, f32x4* acc, float& mrun, float& lrun,
                     int qrow, bool last, int kv0, int cur) {
    // ---- S^T = K Q^T: sac[jj][r] = S[k=kv0+16jj+4g+r][q=r16] (pre-scaled) ----
    f32x4 sac[4] = {};
    __builtin_amdgcn_s_setprio(1);
    #pragma unroll
    for (int kk = 0; kk < 2; ++kk)
      #pragma unroll
      for (int jj = 0; jj < 4; ++jj) {
        int rr = jj * 16 + r16;
        bf16x8 kf = *(const bf16x8*)
            &Ks[cur][rr * 64 + (((kk << 2) + g) ^ (rr & 7)) * 8];
        sac[jj] = __builtin_amdgcn_mfma_f32_16x16x32_bf16(kf, qf[kk], sac[jj],
                                                          0, 0, 0);
      }
    __builtin_amdgcn_s_setprio(0);

    // ---- causal mask (diagonal tile only), per-lane max ----
    float pv[4][4];
    float mt = NEGF;
    #pragma unroll
    for (int jj = 0; jj < 4; ++jj)
      #pragma unroll
      for (int r = 0; r < 4; ++r) {
        float s = sac[jj][r];
        if (last) {
          int kcol = kv0 + jj * 16 + 4 * g + r;
          s = (kcol > qrow) ? NEGF : s;
        }
        pv[jj][r] = s;
        mt = fmaxf(mt, s);
      }
    mt = fmaxf(mt, __shfl_xor(mt, 16));
    mt = fmaxf(mt, __shfl_xor(mt, 32));

    if (__any(mt > mrun)) {          // T13 defer-max (exact: P<=1 when skipped)
      float mnew = fmaxf(mrun, mt);
      float fac = exp2f(mrun - mnew);
      mrun = mnew;
      lrun *= fac;
      #pragma unroll
      for (int j2 = 0; j2 < 4; ++j2)
        #pragma unroll
        for (int r = 0; r < 4; ++r)
          acc[j2][r] *= fac;
    }
    float rs = 0.f;
    #pragma unroll
    for (int jj = 0; jj < 4; ++jj)
      #pragma unroll
      for (int r = 0; r < 4; ++r) {
        float px = exp2f(pv[jj][r] - mrun);
        pv[jj][r] = px;
        rs += px;
      }
    lrun += rs;                      // lane-partial; cross-g reduced at end

    // ---- pack P^T to bf16, store transposed (quad-swizzled dwords) ----
    #pragma unroll
    for (int jj = 0; jj < 4; ++jj)
      #pragma unroll
      for (int rp = 0; rp < 2; ++rp) {
        unsigned w;
        asm("v_cvt_pk_bf16_f32 %0, %1, %2"
            : "=v"(w) : "v"(pv[jj][2 * rp]), "v"(pv[jj][2 * rp + 1]));
        int c = jj * 8 + g * 2 + rp;                       // k/2
        int addr = r16 * 32 + (((c >> 2) ^ (r16 & 7)) << 2) + (c & 3);
        Pld[wq][addr] = w;
      }

    // ---- ctx^T += V^T P ----
    bf16x8 pf[2];
    #pragma unroll
    for (int half = 0; half < 2; ++half) {
      int c = half * 16 + g * 4;
      int addr = r16 * 32 + (((c >> 2) ^ (r16 & 7)) << 2);
      pf[half] = *(const bf16x8*)&Pld[wq][addr];
    }
    __builtin_amdgcn_s_setprio(1);
    #pragma unroll
    for (int j2 = 0; j2 < 4; ++j2)
      #pragma unroll
      for (int half = 0; half < 2; ++half) {
        int dd = j2 * 16 + r16;
        bf16x8 vf = *(const bf16x8*)
            &Vs[cur][dd * 64 + (((half << 2) + g) ^ (dd & 7)) * 8];
        acc[j2] = __builtin_amdgcn_mfma_f32_16x16x32_bf16(vf, pf[half],
                                                          acc[j2], 0, 0, 0);
      }
    __builtin_amdgcn_s_setprio(0);
  };

  STAGE(0, 0);
  __syncthreads();

  for (int t = 0; t < ntH; ++t) {
    const int cur = t & 1;
    if (t + 1 < ntH) STAGE(cur ^ 1, t + 1);   // async prefetch next tile
    const int kv0 = t * 64;

    SUBTILE(qfH, accH, mrunH, lrunH, q0H + r16, t == ntH - 1, kv0, cur);
    if (t < ntL)
      SUBTILE(qfL, accL, mrunL, lrunL, q0L + r16, t == ntL - 1, kv0, cur);

    __syncthreads();   // drains prefetch (vmcnt) + all LDS reads (lgkm)
  }
  // (last barrier above: Ks/Vs now dead -> reuse Ks as epilogue staging)

  // ---- stage normalized ctx tiles [64q][64d] into Ks (chunk-swizzled) ----
  auto STAGE_OUT = [&](f32x4* acc, float lrun, int slot) {
    lrun += __shfl_xor(lrun, 16);
    lrun += __shfl_xor(lrun, 32);
    const float inv = 1.f / lrun;
    const int q = wq * 16 + r16;
    #pragma unroll
    for (int j2 = 0; j2 < 4; ++j2)
      #pragma unroll
      for (int r = 0; r < 4; ++r) {
        int d = j2 * 16 + 4 * g + r;
        int cs = (d >> 3) ^ (q & 7);
        Ks[slot][q * 64 + cs * 8 + (d & 7)] = (__bf16)(acc[j2][r] * inv);
      }
  };
  STAGE_OUT(accH, lrunH, 0);
  STAGE_OUT(accL, lrunL, 1);
  __syncthreads();

  // ---- coalesced 16B stores: 1024 chunks (2 tiles x 64q x 8), 4/thread ----
  #pragma unroll
  for (int i = 0; i < 4; ++i) {
    int c = tid + 256 * i;
    int slot = c >> 9;                       // 0: qH tile, 1: qL tile
    int ql = (c >> 3) & 63, j = c & 7;
    int cs = j ^ (ql & 7);
    bf16x8 vv = *(const bf16x8*)&Ks[slot][ql * 64 + cs * 8];
    int qg = (slot ? p : (31 - p)) * 64 + ql;
    *(bf16x8*)&ctxb[((size_t)(b * SSX + qg)) * DIMX + h * HDX + j * 8] = vv;
  }
}

extern "C" void kernel_launch(void* const* d_in, const int* in_sizes, int n_in,
                              void* d_out, int out_size, void* d_ws,
                              size_t ws_size, hipStream_t stream) {
  const float* x  = (const float*)d_in[0];
  const float* Wq = (const float*)d_in[1];
  const float* bq = (const float*)d_in[2];
  const float* Wk = (const float*)d_in[3];
  const float* bk = (const float*)d_in[4];
  const float* Wv = (const float*)d_in[5];
  const float* bv = (const float*)d_in[6];
  const float* Wo = (const float*)d_in[7];
  const float* bo = (const float*)d_in[8];
  float* out = (float*)d_out;

  char* ws = (char*)d_ws;                       // needs 40 MB
  __bf16* xb    = (__bf16*)(ws);                // 8 MB, reused as ctxb later
  __bf16* wqkvT = (__bf16*)(ws + ((size_t)8  << 20));  // 6 MB
  __bf16* woT   = (__bf16*)(ws + ((size_t)14 << 20));  // 2 MB
  __bf16* qb    = (__bf16*)(ws + ((size_t)16 << 20));  // 8 MB
  __bf16* kb    = (__bf16*)(ws + ((size_t)24 << 20));  // 8 MB
  __bf16* vtb   = (__bf16*)(ws + ((size_t)32 << 20));  // 8 MB (V^T)
  __bf16* ctxb  = xb;   // x dead after QKV GEMM

  k_prep<<<3072, 256, 0, stream>>>(x, Wq, Wk, Wv, Wo, xb, wqkvT, woT);
  k_gemm_qkv<<<768, 256, 0, stream>>>(xb, wqkvT, bq, bk, bv, qb, kb, vtb);
  k_attn<<<512, 256, 0, stream>>>(qb, kb, vtb, ctxb);
  k_gemm_out<<<512, 256, 0, stream>>>(ctxb, woT, bo, out);
}